// Round 2
// baseline (186.344 us; speedup 1.0000x reference)
//
#include <hip/hip_runtime.h>

#define S_LEN   524288
#define IN_D    22
#define HID     9
#define NTAG    4
#define CHUNK   128
#define BURN    64
#define NCHUNK  (S_LEN / CHUNK)   // 4096
#define WPB     4                 // waves per block
#define TILE    16                // x rows per LDS tile
#define ROWF    24                // padded row floats (96 B, 16-aligned)
#define TILEF   (TILE * ROWF)     // 384 floats = 1536 B
#define NLOADS  (TILEF / 64)      // 6 dwords per lane per tile

// DPP quad_perm helpers (VALU-pipe cross-lane within quads of 4)
__device__ __forceinline__ float qrot1(float v) {  // lane gets quad-neighbor +1
  return __int_as_float(__builtin_amdgcn_update_dpp(
      0, __float_as_int(v), 0x39 /*[1,2,3,0]*/, 0xF, 0xF, true));
}
__device__ __forceinline__ float qxor1(float v) {  // lane ^ 1
  return __int_as_float(__builtin_amdgcn_update_dpp(
      0, __float_as_int(v), 0xB1 /*[1,0,3,2]*/, 0xF, 0xF, true));
}
__device__ __forceinline__ float qxor2(float v) {  // lane ^ 2
  return __int_as_float(__builtin_amdgcn_update_dpp(
      0, __float_as_int(v), 0x4E /*[2,3,0,1]*/, 0xF, 0xF, true));
}

__global__ __launch_bounds__(256, 4)
void lstm_chunk_scan(const float* __restrict__ x,
                     const float* __restrict__ w_ih,
                     const float* __restrict__ w_hh,
                     const float* __restrict__ b_ih,
                     const float* __restrict__ b_hh,
                     const float* __restrict__ w_out,
                     const float* __restrict__ b_out,
                     float* __restrict__ out)
{
  __shared__ __align__(16) float lds[WPB * 2 * TILEF];

  const int tid  = threadIdx.x;
  const int wv   = __builtin_amdgcn_readfirstlane(tid >> 6);
  const int lane = tid & 63;
  const int u    = lane >> 2;   // hidden unit (0..8 active)
  const int g    = lane & 3;    // gate: 0=i 1=f 2=g~ 3=o
  const bool act = (u < HID);
  const int row  = act ? (g * HID + u) : 0;   // PyTorch gate-row order

  // register-resident weights
  float wih[IN_D], whh[HID], wo[HID];
#pragma unroll
  for (int k = 0; k < IN_D; ++k) wih[k] = act ? w_ih[row * IN_D + k] : 0.f;
#pragma unroll
  for (int k = 0; k < HID; ++k)  whh[k] = act ? w_hh[row * HID + k] : 0.f;
  const float bias = act ? (b_ih[row] + b_hh[row]) : 0.f;
  const int orow = (lane < NTAG) ? lane : 0;
  float wo_b = b_out[orow];
#pragma unroll
  for (int k = 0; k < HID; ++k)  wo[k] = w_out[orow * HID + k];
  if (lane >= NTAG) { wo_b = 0.f; }

  // unified sigmoid/tanh per-lane constants:
  // v = rcp(1 + exp2(pre*mexp)) * smul + soff
  const float mexp = (g == 2) ? -2.885390082f : -1.442695041f;
  const float smul = (g == 2) ? 2.f : 1.f;
  const float soff = (g == 2) ? -1.f : 0.f;

  const int chunk = __builtin_amdgcn_readfirstlane((int)blockIdx.x * WPB + wv);
  const int start = chunk * CHUNK;
  const int t0    = (start >= BURN) ? (start - BURN) : 0;  // chunk 0 starts exact
  const int nstep = start + CHUNK - t0;                    // 128 or 192
  const int ntile = nstep / TILE;                          // 8 or 12

  float* myl = lds + wv * 2 * TILEF;   // wave-private double buffer

  // per-lane padded-row global offsets for tile staging
  int goff[NLOADS];
#pragma unroll
  for (int cc = 0; cc < NLOADS; ++cc) {
    int slot = cc * 64 + lane;
    int r = slot / ROWF;
    int col = slot - r * ROWF;
    if (col >= IN_D) col = IN_D - 1;   // pad dups (harmless)
    goff[cc] = r * IN_D + col;
  }
  const long XMAX = (long)S_LEN * IN_D - 1;

  float stage[NLOADS];
  { // tile 0 synchronous stage
    long tb = (long)t0 * IN_D;
#pragma unroll
    for (int cc = 0; cc < NLOADS; ++cc) {
      long gi = tb + goff[cc];
      if (gi > XMAX) gi = XMAX;
      stage[cc] = x[gi];
    }
#pragma unroll
    for (int cc = 0; cc < NLOADS; ++cc) myl[cc * 64 + lane] = stage[cc];
  }

  float sh[HID];
#pragma unroll
  for (int k = 0; k < HID; ++k) sh[k] = 0.f;
  float cst = 0.f;

  for (int ti = 0; ti < ntile; ++ti) {
    // issue prefetch of next tile into regs (consumed after 16-step compute)
    {
      long tb = (long)(t0 + (ti + 1) * TILE) * IN_D;
#pragma unroll
      for (int cc = 0; cc < NLOADS; ++cc) {
        long gi = tb + goff[cc];
        if (gi > XMAX) gi = XMAX;
        stage[cc] = x[gi];
      }
    }

    const float* rb = myl + (ti & 1) * TILEF;
    const int tbase = t0 + ti * TILE;
    const bool outp = (tbase >= start);   // uniform per tile (BURN % TILE == 0)

#pragma unroll
    for (int s = 0; s < TILE; ++s) {
      const float* xr = rb + s * ROWF;
      float xv[22];
      *(float4*)(&xv[0])  = *(const float4*)(xr + 0);    // ds_read_b128 broadcast
      *(float4*)(&xv[4])  = *(const float4*)(xr + 4);
      *(float4*)(&xv[8])  = *(const float4*)(xr + 8);
      *(float4*)(&xv[12]) = *(const float4*)(xr + 12);
      *(float4*)(&xv[16]) = *(const float4*)(xr + 16);
      *(float2*)(&xv[20]) = *(const float2*)(xr + 20);

      float a0 = bias, a1 = 0.f;
#pragma unroll
      for (int k = 0; k < IN_D; ++k) {
        if (k & 1) a1 = fmaf(xv[k], wih[k], a1);
        else       a0 = fmaf(xv[k], wih[k], a0);
      }
#pragma unroll
      for (int k = 0; k < HID; ++k) {   // sh[k] are SGPRs: 1 SGPR operand per FMA
        if (k & 1) a1 = fmaf(sh[k], whh[k], a1);
        else       a0 = fmaf(sh[k], whh[k], a0);
      }
      float pre = a0 + a1;

      float ex = __builtin_amdgcn_exp2f(pre * mexp);
      float gv = fmaf(__builtin_amdgcn_rcpf(1.f + ex), smul, soff);

      float fg = qrot1(gv);   // lane g=0 view: fg=f
      float gg = qrot1(fg);   //                gg=g~
      float og = qrot1(gg);   //                og=o
      cst = fmaf(fg, cst, gv * gg);           // valid on g==0 lanes
      float e2 = __builtin_amdgcn_exp2f(cst * -2.885390082f);
      float th = fmaf(__builtin_amdgcn_rcpf(1.f + e2), 2.f, -1.f);  // tanh(c)
      float hv = og * th;                     // h_u on lanes 4u

#pragma unroll
      for (int k = 0; k < HID; ++k)
        sh[k] = __int_as_float(
            __builtin_amdgcn_readlane(__float_as_int(hv), 4 * k));

      if (outp) {
        float acc = wo_b;
#pragma unroll
        for (int k = 0; k < HID; ++k) acc = fmaf(sh[k], wo[k], acc);
        float m = fmaxf(acc, qxor1(acc));
        m = fmaxf(m, qxor2(m));
        float xm = acc - m;
        float ee = __builtin_amdgcn_exp2f(xm * 1.442695041f);
        float sm = ee + qxor1(ee);
        sm = sm + qxor2(sm);
        float res = fmaf(-0.69314718056f, __builtin_amdgcn_logf(sm), xm);
        if (lane < NTAG) out[(long)(tbase + s) * NTAG + lane] = res;
      }
    }

    // land the prefetched tile into the other buffer (vmcnt waited here,
    // ~2000 cycles after issue -> HBM latency hidden)
    float* wb = myl + ((ti + 1) & 1) * TILEF;
#pragma unroll
    for (int cc = 0; cc < NLOADS; ++cc) wb[cc * 64 + lane] = stage[cc];
  }
}

extern "C" void kernel_launch(void* const* d_in, const int* in_sizes, int n_in,
                              void* d_out, int out_size, void* d_ws, size_t ws_size,
                              hipStream_t stream) {
  (void)in_sizes; (void)n_in; (void)d_ws; (void)ws_size; (void)out_size;
  const float* x     = (const float*)d_in[0];
  const float* w_ih  = (const float*)d_in[1];
  const float* w_hh  = (const float*)d_in[2];
  const float* b_ih  = (const float*)d_in[3];
  const float* b_hh  = (const float*)d_in[4];
  const float* w_out = (const float*)d_in[5];
  const float* b_out = (const float*)d_in[6];
  float* out = (float*)d_out;

  hipLaunchKernelGGL(lstm_chunk_scan, dim3(NCHUNK / WPB), dim3(256), 0, stream,
                     x, w_ih, w_hh, b_ih, b_hh, w_out, b_out, out);
}